// Round 12
// baseline (99.136 us; speedup 1.0000x reference)
//
#include <hip/hip_runtime.h>
#include <stdint.h>

// Chain min-cut / Viterbi, exact fp32 emulation of the reference scan via the
// scalar d-recurrence (d = a0 - a1 of the renormalized carry).
// Round 12: r10 structure (SEG=32, single kernel, block-local fill, in-block
// suffix-carry walk) with __launch_bounds__(256,6): 6 blocks/CU = 24 waves/CU
// (vs r10's 4) under a ~85-VGPR budget. r11's SEG=16 @ (256,8) spilled and
// regressed; this is the intermediate occupancy tier.

#define LAM 0.75f
constexpr int N_TOTAL = 8388608;
constexpr int SEG = 32;
constexpr int NSEG = N_TOTAL / SEG;     // 262144 segments (32-bit words)
constexpr int NBLK = NSEG / 256;        // 1024 blocks, 8192 nodes each

// Bit-exact renormalized step: d' = fl(fl(p+e0) - fl(fl(1-p)+e1))
__device__ __forceinline__ float dstep(float d, float p) {
    float e0 = fminf(fmaxf(d, 0.0f), LAM);
    float e1 = fminf(fmaxf(-d, 0.0f), LAM);
    return (p + e0) - ((1.0f - p) + e1);
}

// Exact d at the END of segment 0 (special non-renormalized first step).
__device__ float seg0_end(const float* __restrict__ p) {
    float p0 = p[0];
    float a0 = p0, a1 = 1.0f - p0;
    float t0 = fminf(a0, a1 + LAM);
    float t1 = fminf(a1, a0 + LAM);
    float p1 = p[1];
    float d = (p1 + t0) - ((1.0f - p1) + t1);   // d_1 (renormalized)
    for (int i = 2; i < SEG; ++i) d = dstep(d, p[i]);
    return d;
}

// Sign bit of the first set bit of m (offset sh into wg); fallback if m==0.
// Defined for all m: ctz operand never 0 (identity for m!=0), shift masked.
__device__ __forceinline__ uint32_t pick_bit(uint32_t m, uint32_t wg, int sh,
                                             uint32_t fallback) {
    uint32_t mm = m ? m : 1u;
    int idx = (sh + __builtin_ctz(mm)) & 31;
    uint32_t hit = (wg >> idx) & 1u;
    return m ? hit : fallback;
}

union SegU { float4 q[8]; float f[32]; };
union WalkU { float4 q[4]; float f[16]; };

__global__ __launch_bounds__(256, 6) void k_main(const float* __restrict__ p,
        int* __restrict__ out) {
    __shared__ float s_dh[256];
    __shared__ uint8_t s_ok[256];
    __shared__ uint32_t lev[256];
    __shared__ uint32_t lsg[256];
    __shared__ int lC[256];
    __shared__ int s_carry;
    const int t = threadIdx.x;
    const int b = blockIdx.x;
    const int s = b * 256 + t;

    SegU u;
    const float4* g4 = (const float4*)(p + (size_t)s * SEG);
    #pragma unroll
    for (int i = 0; i < 8; ++i) u.q[i] = g4[i];   // 8 independent loads up front

    // thread 255: prefetch next block's first 16 floats for the suffix walk.
    WalkU wu;
    #pragma unroll
    for (int i = 0; i < 4; ++i) wu.q[i] = make_float4(1.0f, 1.0f, 1.0f, 1.0f);
    if (t == 255 && b + 1 < NBLK) {
        const float4* nx = (const float4*)(p + (size_t)(b + 1) * 8192);
        #pragma unroll
        for (int i = 0; i < 4; ++i) wu.q[i] = nx[i];
    }

    // ---- Phase A: sandwich summary (two interleaved independent chains) ----
    // Map is a shift inside (-lam,lam), CONSTANT once the clamp saturates ->
    // extremes coalesce bitwise => exact constant map (P(fail) ~ 0.75^32).
    float dh = 2.0f, dl = -2.0f;
    #pragma unroll
    for (int i = 0; i < SEG; ++i) {
        float pi = u.f[i];
        dh = dstep(dh, pi);
        dl = dstep(dl, pi);
    }
    s_dh[t] = dh;
    s_ok[t] = (dh == dl) ? 1 : 0;
    __syncthreads();

    // ---- Phase B: resolve exact entry d, classify own segment ----
    float d = 0.0f;
    uint32_t em = 0, gm = 0;
    if (s == 0) {
        float p0 = u.f[0];
        float a0 = p0, a1 = 1.0f - p0;
        bool f1 = (a1 + LAM) < a0;                // node-0 decisions (non-renorm)
        bool f0 = (a0 + LAM) < a1;
        em |= (uint32_t)(f1 || f0); gm |= (uint32_t)f1;
        float t0 = fminf(a0, a1 + LAM);
        float t1 = fminf(a1, a0 + LAM);
        float p1 = u.f[1];
        d = (p1 + t0) - ((1.0f - p1) + t1);       // d_1
        em |= (uint32_t)(fabsf(d) > LAM) << 1;
        gm |= (uint32_t)(d > LAM) << 1;
        #pragma unroll
        for (int i = 2; i < SEG; ++i) {
            d = dstep(d, u.f[i]);
            em |= (uint32_t)(fabsf(d) > LAM) << i;
            gm |= (uint32_t)(d > LAM) << i;
        }
    } else {
        int back = t - 1;
        while (back >= 0 && !s_ok[back]) --back;  // common: stops immediately
        int startSeg;
        if (back >= 0) {
            d = s_dh[back];
            startSeg = b * 256 + back;
        } else {
            // cross-block: recompute predecessor summaries from global (rare >1 iter)
            int v = b * 256 - 1;
            for (;;) {
                if (v == 0) { d = seg0_end(p); startSeg = 0; break; }
                const float4* gv = (const float4*)(p + (size_t)v * SEG);
                float h = 2.0f, l = -2.0f;
                for (int i = 0; i < 8; ++i) {
                    float4 q = gv[i];
                    h = dstep(h, q.x); l = dstep(l, q.x);
                    h = dstep(h, q.y); l = dstep(l, q.y);
                    h = dstep(h, q.z); l = dstep(l, q.z);
                    h = dstep(h, q.w); l = dstep(l, q.w);
                }
                if (h == l) { d = h; startSeg = v; break; }
                --v;
            }
        }
        // exact replay of intermediate non-constant segments (rare; L1/L2-hot)
        for (int v = startSeg + 1; v < s; ++v) {
            const float* sv = p + (size_t)v * SEG;
            for (int i = 0; i < SEG; ++i) d = dstep(d, sv[i]);
        }
        #pragma unroll
        for (int i = 0; i < SEG; ++i) {
            d = dstep(d, u.f[i]);
            em |= (uint32_t)(fabsf(d) > LAM) << i;
            gm |= (uint32_t)(d > LAM) << i;
        }
    }
    if (s == NSEG - 1) {                          // forced event at N-1: final label
        em |= 0x80000000u;
        gm = (d > 0.0f) ? (gm | 0x80000000u) : (gm & 0x7FFFFFFFu);
    }
    lev[t] = em;
    lsg[t] = gm;
    __syncthreads();

    // ---- per-word local carry scan (first event in later words of block) ----
    int cur = 0; bool found = false;
    for (int v = t + 1; v < 256; ++v) {           // expected ~1 iteration
        uint32_t evv = lev[v];
        if (evv) {
            cur = (int)pick_bit(evv, lsg[v], 0, 0u);
            found = true;
            break;
        }
    }

    // ---- thread 255: block-suffix carry via exact walk into next block ----
    if (t == 255) {
        int c = 0;
        if (b + 1 < NBLK) {                       // last block: suffix empty (forced bit31)
            float dd = d;                         // exact chain state at block end
            bool done = false;
            #pragma unroll
            for (int i = 0; i < 16; ++i) {        // prefetched fast path (P(miss) ~1%)
                if (!done) {
                    dd = dstep(dd, wu.f[i]);
                    if (fabsf(dd) > LAM) { c = (dd > LAM) ? 1 : 0; done = true; }
                }
            }
            if (!done) {
                const int base = (b + 1) * 8192 + 16;
                const int rem = N_TOTAL - base;
                for (int k = 0; k < rem; ++k) {   // rare scalar tail (L2-hot)
                    dd = dstep(dd, p[base + k]);
                    if (fabsf(dd) > LAM) { c = (dd > LAM) ? 1 : 0; done = true; break; }
                }
                if (!done) c = (dd > 0.0f) ? 1 : 0;  // reached N-1: final label
            }
        }
        s_carry = c;
    }
    __syncthreads();
    if (!found) cur = s_carry;
    lC[t] = cur;
    __syncthreads();

    // ---- Phase C: coalesced label writes straight from LDS masks ----
    int4* o4 = (int4*)out + (size_t)b * 2048;     // block covers 2048 int4 chunks
    #pragma unroll
    for (int i = 0; i < 8; ++i) {
        int c = i * 256 + t;                      // coalesced: consecutive lanes -> consecutive 16B
        int wl = c >> 3;                          // word within block (8 chunks/word)
        int bb = (c & 7) * 4;                     // starting bit of this chunk (<=28)
        uint32_t we = lev[wl], wg = lsg[wl];      // broadcast reads across 8 lanes
        uint32_t wc = (uint32_t)lC[wl];
        int4 r;
        r.x = (int)pick_bit(we >> (bb + 0), wg, bb + 0, wc);
        r.y = (int)pick_bit(we >> (bb + 1), wg, bb + 1, wc);
        r.z = (int)pick_bit(we >> (bb + 2), wg, bb + 2, wc);
        r.w = (int)pick_bit(we >> (bb + 3), wg, bb + 3, wc);
        o4[c] = r;
    }
}

extern "C" void kernel_launch(void* const* d_in, const int* in_sizes, int n_in,
                              void* d_out, int out_size, void* d_ws, size_t ws_size,
                              hipStream_t stream) {
    (void)in_sizes; (void)n_in; (void)out_size; (void)d_ws; (void)ws_size;
    const float* p = (const float*)d_in[0];
    int* out = (int*)d_out;

    k_main<<<dim3(NBLK), dim3(256), 0, stream>>>(p, out);
}

// Round 13
// 84.847 us; speedup vs baseline: 1.1684x; 1.1684x over previous
//
#include <hip/hip_runtime.h>
#include <stdint.h>

// Chain min-cut / Viterbi, exact fp32 emulation of the reference scan via the
// scalar d-recurrence (d = a0 - a1 of the renormalized carry).
// Round 13: REVERT to the round-10 configuration (best: 85.8 us, absmax 0).
// SEG=32, single kernel, __launch_bounds__(256,4) = the only non-spilling
// occupancy tier: gfx950 waves/SIMD quantize at VGPR 64/128/256 (m69), this
// kernel's live set is ~100 VGPRs, so 5-8 waves/SIMD all force the 64-VGPR
// tier -> spill (r11: 93.8 us, r12: 99.1 us w/ 37 MB scratch WRITE traffic).
// Structure: per-thread 32-node segment in registers; monotone hi/lo sandwich
// summary (step map forgets input once the clamp saturates; bitwise-equal
// extremes => exact constant map); block-local entry resolution via LDS;
// event/sign bitmask classify; in-block suffix-carry walk by thread 255;
// coalesced int4 label writes straight from LDS.

#define LAM 0.75f
constexpr int N_TOTAL = 8388608;
constexpr int SEG = 32;
constexpr int NSEG = N_TOTAL / SEG;     // 262144 segments (32-bit words)
constexpr int NBLK = NSEG / 256;        // 1024 blocks, 8192 nodes each

// Bit-exact renormalized step: d' = fl(fl(p+e0) - fl(fl(1-p)+e1))
__device__ __forceinline__ float dstep(float d, float p) {
    float e0 = fminf(fmaxf(d, 0.0f), LAM);
    float e1 = fminf(fmaxf(-d, 0.0f), LAM);
    return (p + e0) - ((1.0f - p) + e1);
}

// Exact d at the END of segment 0 (special non-renormalized first step).
__device__ float seg0_end(const float* __restrict__ p) {
    float p0 = p[0];
    float a0 = p0, a1 = 1.0f - p0;
    float t0 = fminf(a0, a1 + LAM);
    float t1 = fminf(a1, a0 + LAM);
    float p1 = p[1];
    float d = (p1 + t0) - ((1.0f - p1) + t1);   // d_1 (renormalized)
    for (int i = 2; i < SEG; ++i) d = dstep(d, p[i]);
    return d;
}

// Sign bit of the first set bit of m (offset sh into wg); fallback if m==0.
// Defined for all m: ctz operand never 0 (identity for m!=0), shift masked.
__device__ __forceinline__ uint32_t pick_bit(uint32_t m, uint32_t wg, int sh,
                                             uint32_t fallback) {
    uint32_t mm = m ? m : 1u;
    int idx = (sh + __builtin_ctz(mm)) & 31;
    uint32_t hit = (wg >> idx) & 1u;
    return m ? hit : fallback;
}

union SegU { float4 q[8]; float f[32]; };
union WalkU { float4 q[4]; float f[16]; };

__global__ __launch_bounds__(256, 4) void k_main(const float* __restrict__ p,
        int* __restrict__ out) {
    __shared__ float s_dh[256];
    __shared__ uint8_t s_ok[256];
    __shared__ uint32_t lev[256];
    __shared__ uint32_t lsg[256];
    __shared__ int lC[256];
    __shared__ int s_carry;
    const int t = threadIdx.x;
    const int b = blockIdx.x;
    const int s = b * 256 + t;

    SegU u;
    const float4* g4 = (const float4*)(p + (size_t)s * SEG);
    #pragma unroll
    for (int i = 0; i < 8; ++i) u.q[i] = g4[i];   // 8 independent loads up front

    // thread 255: prefetch next block's first 16 floats for the suffix walk.
    // Fully initialized for ALL threads first (no UB read path).
    WalkU wu;
    #pragma unroll
    for (int i = 0; i < 4; ++i) wu.q[i] = make_float4(1.0f, 1.0f, 1.0f, 1.0f);
    if (t == 255 && b + 1 < NBLK) {
        const float4* nx = (const float4*)(p + (size_t)(b + 1) * 8192);
        #pragma unroll
        for (int i = 0; i < 4; ++i) wu.q[i] = nx[i];
    }

    // ---- Phase A: sandwich summary (two interleaved independent chains) ----
    float dh = 2.0f, dl = -2.0f;
    #pragma unroll
    for (int i = 0; i < SEG; ++i) {
        float pi = u.f[i];
        dh = dstep(dh, pi);
        dl = dstep(dl, pi);
    }
    s_dh[t] = dh;
    s_ok[t] = (dh == dl) ? 1 : 0;
    __syncthreads();

    // ---- Phase B: resolve exact entry d, classify own segment ----
    float d = 0.0f;
    uint32_t em = 0, gm = 0;
    if (s == 0) {
        float p0 = u.f[0];
        float a0 = p0, a1 = 1.0f - p0;
        bool f1 = (a1 + LAM) < a0;                // node-0 decisions (non-renorm)
        bool f0 = (a0 + LAM) < a1;
        em |= (uint32_t)(f1 || f0); gm |= (uint32_t)f1;
        float t0 = fminf(a0, a1 + LAM);
        float t1 = fminf(a1, a0 + LAM);
        float p1 = u.f[1];
        d = (p1 + t0) - ((1.0f - p1) + t1);       // d_1
        em |= (uint32_t)(fabsf(d) > LAM) << 1;
        gm |= (uint32_t)(d > LAM) << 1;
        #pragma unroll
        for (int i = 2; i < SEG; ++i) {
            d = dstep(d, u.f[i]);
            em |= (uint32_t)(fabsf(d) > LAM) << i;
            gm |= (uint32_t)(d > LAM) << i;
        }
    } else {
        int back = t - 1;
        while (back >= 0 && !s_ok[back]) --back;  // common: stops immediately
        int startSeg;
        if (back >= 0) {
            d = s_dh[back];
            startSeg = b * 256 + back;
        } else {
            // cross-block: recompute predecessor summaries from global (rare >1 iter)
            int v = b * 256 - 1;
            for (;;) {
                if (v == 0) { d = seg0_end(p); startSeg = 0; break; }
                const float4* gv = (const float4*)(p + (size_t)v * SEG);
                float h = 2.0f, l = -2.0f;
                for (int i = 0; i < 8; ++i) {
                    float4 q = gv[i];
                    h = dstep(h, q.x); l = dstep(l, q.x);
                    h = dstep(h, q.y); l = dstep(l, q.y);
                    h = dstep(h, q.z); l = dstep(l, q.z);
                    h = dstep(h, q.w); l = dstep(l, q.w);
                }
                if (h == l) { d = h; startSeg = v; break; }
                --v;
            }
        }
        // exact replay of intermediate non-constant segments (rare; L1/L2-hot)
        for (int v = startSeg + 1; v < s; ++v) {
            const float* sv = p + (size_t)v * SEG;
            for (int i = 0; i < SEG; ++i) d = dstep(d, sv[i]);
        }
        #pragma unroll
        for (int i = 0; i < SEG; ++i) {
            d = dstep(d, u.f[i]);
            em |= (uint32_t)(fabsf(d) > LAM) << i;
            gm |= (uint32_t)(d > LAM) << i;
        }
    }
    if (s == NSEG - 1) {                          // forced event at N-1: final label
        em |= 0x80000000u;
        gm = (d > 0.0f) ? (gm | 0x80000000u) : (gm & 0x7FFFFFFFu);
    }
    lev[t] = em;
    lsg[t] = gm;
    __syncthreads();

    // ---- per-word local carry scan (first event in later words of block) ----
    int cur = 0; bool found = false;
    for (int v = t + 1; v < 256; ++v) {           // expected ~1 iteration
        uint32_t evv = lev[v];
        if (evv) {
            cur = (int)pick_bit(evv, lsg[v], 0, 0u);
            found = true;
            break;
        }
    }

    // ---- thread 255: block-suffix carry via exact walk into next block ----
    if (t == 255) {
        int c = 0;
        if (b + 1 < NBLK) {                       // last block: suffix empty (forced bit31)
            float dd = d;                         // exact chain state at block end
            bool done = false;
            #pragma unroll
            for (int i = 0; i < 16; ++i) {        // prefetched fast path (P(miss) ~1%)
                if (!done) {
                    dd = dstep(dd, wu.f[i]);
                    if (fabsf(dd) > LAM) { c = (dd > LAM) ? 1 : 0; done = true; }
                }
            }
            if (!done) {
                const int base = (b + 1) * 8192 + 16;
                const int rem = N_TOTAL - base;
                for (int k = 0; k < rem; ++k) {   // rare scalar tail (L2-hot)
                    dd = dstep(dd, p[base + k]);
                    if (fabsf(dd) > LAM) { c = (dd > LAM) ? 1 : 0; done = true; break; }
                }
                if (!done) c = (dd > 0.0f) ? 1 : 0;  // reached N-1: final label
            }
        }
        s_carry = c;
    }
    __syncthreads();
    if (!found) cur = s_carry;
    lC[t] = cur;
    __syncthreads();

    // ---- Phase C: coalesced label writes straight from LDS masks ----
    int4* o4 = (int4*)out + (size_t)b * 2048;     // block covers 2048 int4 chunks
    #pragma unroll
    for (int i = 0; i < 8; ++i) {
        int c = i * 256 + t;                      // coalesced: consecutive lanes -> consecutive 16B
        int wl = c >> 3;                          // word within block (8 chunks/word)
        int bb = (c & 7) * 4;                     // starting bit of this chunk (<=28)
        uint32_t we = lev[wl], wg = lsg[wl];      // broadcast reads across 8 lanes
        uint32_t wc = (uint32_t)lC[wl];
        int4 r;
        r.x = (int)pick_bit(we >> (bb + 0), wg, bb + 0, wc);
        r.y = (int)pick_bit(we >> (bb + 1), wg, bb + 1, wc);
        r.z = (int)pick_bit(we >> (bb + 2), wg, bb + 2, wc);
        r.w = (int)pick_bit(we >> (bb + 3), wg, bb + 3, wc);
        o4[c] = r;
    }
}

extern "C" void kernel_launch(void* const* d_in, const int* in_sizes, int n_in,
                              void* d_out, int out_size, void* d_ws, size_t ws_size,
                              hipStream_t stream) {
    (void)in_sizes; (void)n_in; (void)out_size; (void)d_ws; (void)ws_size;
    const float* p = (const float*)d_in[0];
    int* out = (int*)d_out;

    k_main<<<dim3(NBLK), dim3(256), 0, stream>>>(p, out);
}